// Round 9
// baseline (618.707 us; speedup 1.0000x reference)
//
#include <hip/hip_runtime.h>

#define DD 64
#define NBKT 1024
#define CHUNK 8192
#define CAP_B 6656    // bucket capacity in edges (mean 5371, ~17 sigma slack)

struct SegCfg {
    int qbase[4];   // first bucket id of segment
    int rpb[4];     // rows per bucket
    float inv[4];   // 1.f / rpb
    int soff[4];    // global row offset of segment
    int rows[4];    // rows in segment
};

// ---------- K1 v3: two-pass multisplit, zero staging ----------
// Pass 1 counts bucket occupancy (loads d only, no saved state). One global
// atomic per non-empty bucket reserves the block's run. Pass 2 re-decodes and
// writes each packed edge directly to its final bkt slot via an LDS cursor.
// No ord[] stage (64KB LDS gone), no block scan (18 barriers gone), no
// val[16]/qv[16]/rv[16] register arrays (spill pressure gone). LDS = 12 KB,
// tiny VGPR -> 4 blocks/CU. Line-level write coalescing now relies on L2
// write-combining of each block's dense ~64B runs.
__global__ void __launch_bounds__(512, 8)
split_kernel(const int* __restrict__ dA, const int* __restrict__ sA, const int* __restrict__ tA,
             const int* __restrict__ dB, const int* __restrict__ sB, const int* __restrict__ tB,
             const int* __restrict__ dC, const int* __restrict__ sC,
             const int* __restrict__ dD, const int* __restrict__ sD,
             int nA, int nB, int nC, int nD,
             SegCfg cfg, int* __restrict__ gcur, unsigned long long* __restrict__ bkt) {
    __shared__ int cnt[NBKT];   // pass-1 counts
    __shared__ int cur[NBKT];   // pass-2 cursors
    __shared__ int gb[NBKT];    // global bases
    int t = threadIdx.x;
    int Etot = nA + nB + nC + nD;
    int base = blockIdx.x * CHUNK;
    if (base >= Etot) return;

    cnt[t] = 0; cnt[t + 512] = 0;
    cur[t] = 0; cur[t + 512] = 0;
    __syncthreads();

    // pass 1: count (d only)
    for (int k = 0; k < 16; ++k) {
        int i = base + k * 512 + t;
        if (i >= Etot) break;
        int j = i, d, seg;
        if (j < nA)              { seg = 0; d = dA[j]; }
        else if ((j -= nA) < nB) { seg = 1; d = dB[j]; }
        else if ((j -= nB) < nC) { seg = 2; d = dC[j]; }
        else { j -= nC;            seg = 3; d = dD[j]; }
        int rpb = cfg.rpb[seg];
        int q = (int)((float)d * cfg.inv[seg]);
        if (d >= (q + 1) * rpb) ++q;
        else if (d < q * rpb) --q;
        atomicAdd(&cnt[q + cfg.qbase[seg]], 1);
    }
    __syncthreads();

    // reserve global runs (2 buckets/thread)
    {
        int c0 = cnt[2 * t], c1 = cnt[2 * t + 1];
        gb[2 * t]     = c0 ? atomicAdd(&gcur[2 * t], c0) : 0;
        gb[2 * t + 1] = c1 ? atomicAdd(&gcur[2 * t + 1], c1) : 0;
    }
    __syncthreads();

    // pass 2: re-decode, rank via LDS cursor, write to final slot
    for (int k = 0; k < 16; ++k) {
        int i = base + k * 512 + t;
        if (i >= Etot) break;
        int j = i, d, seg, pv;
        if (j < nA)              { seg = 0; d = dA[j]; pv = sA[j] | (tA[j] << 20); }
        else if ((j -= nA) < nB) { seg = 1; d = dB[j]; pv = sB[j] | (tB[j] << 20); }
        else if ((j -= nB) < nC) { seg = 2; d = dC[j]; pv = sC[j]; }
        else { j -= nC;            seg = 3; d = dD[j]; pv = sD[j]; }
        int rpb = cfg.rpb[seg];
        int q = (int)((float)d * cfg.inv[seg]);
        if (d >= (q + 1) * rpb) ++q;
        else if (d < q * rpb) --q;
        int g = d + cfg.soff[seg];
        q += cfg.qbase[seg];
        int pos = atomicAdd(&cur[q], 1);
        int idx = gb[q] + pos;
        if (idx < CAP_B)   // capacity clamp: overflow drops, never faults
            bkt[(size_t)q * CAP_B + idx] = ((unsigned long long)g << 25) | (unsigned)pv;
    }
}

// ---------- K2: fused per-bucket counting sort + gather-reduce (unchanged) ----------
__global__ void __launch_bounds__(512, 2)
sort_gather(const unsigned long long* __restrict__ bkt, const int* __restrict__ gcur,
            SegCfg cfg,
            const float* __restrict__ entity_emb, const float* __restrict__ user_emb,
            const float* __restrict__ weight,
            float* __restrict__ out, float* __restrict__ usr_out,
            float* __restrict__ iu, float* __restrict__ ui) {
    __shared__ int cnt[1024];        // 4 KB (rows/bucket <= 807)
    __shared__ int part[512];        // 2 KB
    __shared__ int stage[CAP_B];     // 26 KB
    int b = blockIdx.x, t = threadIdx.x;

    int seg = 0;
    if (b >= cfg.qbase[3]) seg = 3;
    else if (b >= cfg.qbase[2]) seg = 2;
    else if (b >= cfg.qbase[1]) seg = 1;
    int lb = b - cfg.qbase[seg];
    int row0 = cfg.soff[seg] + lb * cfg.rpb[seg];
    int nr = cfg.rows[seg] - lb * cfg.rpb[seg];
    if (nr > cfg.rpb[seg]) nr = cfg.rpb[seg];
    int n = gcur[b];
    if (n > CAP_B) n = CAP_B;        // overflow guard (matches split clamp)
    const unsigned long long* src = bkt + (size_t)b * CAP_B;

    // block-uniform source table and destination base
    const float* emb = (seg == 0 || seg == 3) ? entity_emb : user_emb;
    float* dbase;
    if (seg == 0)      dbase = out     + (size_t)row0 * DD;
    else if (seg == 1) dbase = usr_out + (size_t)(row0 - cfg.soff[1]) * DD;
    else if (seg == 2) dbase = iu      + (size_t)(row0 - cfg.soff[2]) * DD;
    else               dbase = ui      + (size_t)(row0 - cfg.soff[3]) * DD;

    cnt[t] = 0; cnt[t + 512] = 0;
    __syncthreads();
    for (int i = t; i < n; i += 512) {
        int g = (int)(src[i] >> 25);
        atomicAdd(&cnt[g - row0], 1);
    }
    __syncthreads();

    // exclusive scan of cnt[0..1024): 2 elems/thread + scan of partials
    {
        int c0 = cnt[2 * t], c1 = cnt[2 * t + 1];
        int s2 = c0 + c1;
        part[t] = s2;
        __syncthreads();
        for (int off = 1; off < 512; off <<= 1) {
            int y = (t >= off) ? part[t - off] : 0;
            __syncthreads();
            part[t] += y;
            __syncthreads();
        }
        int run = part[t] - s2;
        cnt[2 * t] = run;
        cnt[2 * t + 1] = run + c0;
    }
    __syncthreads();

    // scatter payloads into LDS stage (cnt consumed as cursors -> cnt[r] = row end)
    for (int i = t; i < n; i += 512) {
        unsigned long long v = src[i];
        int lr = (int)(v >> 25) - row0;
        int pos = atomicAdd(&cnt[lr], 1);
        stage[pos] = (int)(v & 0x1FFFFFF);
    }
    __syncthreads();

    // per-row gather-reduce: wave per row, payload broadcast from LDS
    int wv = t >> 6, lane = t & 63;
    for (int r = wv; r < nr; r += 8) {
        int start = (r == 0) ? 0 : cnt[r - 1];
        int end = cnt[r];
        float acc = 0.f;
        for (int base = start; base < end; base += 64) {
            int m = end - base; if (m > 64) m = 64;
            int pv = (lane < m) ? stage[base + lane] : 0;
            int j = 0;
            for (; j + 4 <= m; j += 4) {
                int p0 = __builtin_amdgcn_readlane(pv, j);
                int p1 = __builtin_amdgcn_readlane(pv, j + 1);
                int p2 = __builtin_amdgcn_readlane(pv, j + 2);
                int p3 = __builtin_amdgcn_readlane(pv, j + 3);
                const float* r0 = emb + (((unsigned)p0 & 0xFFFFFu) << 6);
                const float* r1 = emb + (((unsigned)p1 & 0xFFFFFu) << 6);
                const float* r2 = emb + (((unsigned)p2 & 0xFFFFFu) << 6);
                const float* r3 = emb + (((unsigned)p3 & 0xFFFFFu) << 6);
                float e0 = r0[lane], w0 = weight[(((unsigned)p0 >> 20) << 6) + lane];
                float e1 = r1[lane], w1 = weight[(((unsigned)p1 >> 20) << 6) + lane];
                float e2 = r2[lane], w2 = weight[(((unsigned)p2 >> 20) << 6) + lane];
                float e3 = r3[lane], w3 = weight[(((unsigned)p3 >> 20) << 6) + lane];
                acc += e0 * w0; acc += e1 * w1; acc += e2 * w2; acc += e3 * w3;
            }
            for (; j < m; ++j) {
                int pj = __builtin_amdgcn_readlane(pv, j);
                const float* rj = emb + (((unsigned)pj & 0xFFFFFu) << 6);
                acc += rj[lane] * weight[(((unsigned)pj >> 20) << 6) + lane];
            }
        }
        int deg = end - start;
        dbase[(size_t)r * DD + lane] = acc / (float)(deg > 0 ? deg : 1);
    }
}

// ---------- gated fusion v2 (unchanged): W in VGPRs, activations via s_loads ----------
__global__ void __launch_bounds__(256)
gate_fuse_kernel(const float* __restrict__ a_, const float* __restrict__ b_,
                 const float* __restrict__ gA, const float* __restrict__ gB,
                 float* __restrict__ out, int n_rows) {
    int lane = threadIdx.x & 63;
    float wa[DD], wb[DD];
    {
        const float4* ga4 = (const float4*)(gA + (lane << 6));
        const float4* gb4 = (const float4*)(gB + (lane << 6));
#pragma unroll
        for (int k4 = 0; k4 < 16; ++k4) {
            float4 va = ga4[k4];
            float4 vb = gb4[k4];
            wa[4 * k4 + 0] = va.x; wa[4 * k4 + 1] = va.y;
            wa[4 * k4 + 2] = va.z; wa[4 * k4 + 3] = va.w;
            wb[4 * k4 + 0] = vb.x; wb[4 * k4 + 1] = vb.y;
            wb[4 * k4 + 2] = vb.z; wb[4 * k4 + 3] = vb.w;
        }
    }
    int wid = blockIdx.x * (blockDim.x >> 6) + (threadIdx.x >> 6);
    int nw = gridDim.x * (blockDim.x >> 6);
    for (int row = wid; row < n_rows; row += nw) {
        int row_s = __builtin_amdgcn_readfirstlane(row);
        const float* ar = a_ + ((size_t)row_s << 6);
        const float* br = b_ + ((size_t)row_s << 6);
        float z = 0.f;
#pragma unroll
        for (int k = 0; k < DD; ++k) z = fmaf(ar[k], wa[k], z);
#pragma unroll
        for (int k = 0; k < DD; ++k) z = fmaf(br[k], wb[k], z);
        float g = 1.f / (1.f + expf(-z));
        float av = ar[lane], bv = br[lane];
        out[((size_t)row_s << 6) + lane] = g * av + (1.f - g) * bv;
    }
}

extern "C" void kernel_launch(void* const* d_in, const int* in_sizes, int n_in,
                              void* d_out, int out_size, void* d_ws, size_t ws_size,
                              hipStream_t stream) {
    const float* entity_emb = (const float*)d_in[0];
    const float* user_emb   = (const float*)d_in[1];
    const float* weight     = (const float*)d_in[2];
    const float* g1         = (const float*)d_in[3];
    const float* g2         = (const float*)d_in[4];
    const float* g3         = (const float*)d_in[5];
    const int* edge_index  = (const int*)d_in[6];
    const int* edge_type   = (const int*)d_in[7];
    const int* uedge_index = (const int*)d_in[8];
    const int* uedge_type  = (const int*)d_in[9];
    const int* mat_row     = (const int*)d_in[10];
    const int* mat_col     = (const int*)d_in[11];

    const int n_entities   = in_sizes[0] / DD;  // 180000
    const int n_user_nodes = in_sizes[1] / DD;  // 150000
    const int nA           = in_sizes[7];       // 1500000
    const int nB           = in_sizes[9];       // 1000000
    const int nM           = in_sizes[10];      // 1500000
    const int n_items      = 50000;
    const int n_users      = 100000;

    const int offB = n_entities;                // 180000
    const int offC = offB + n_user_nodes;       // 330000
    const int offD = offC + n_items;            // 380000
    const int Etot = nA + nB + nM + nM;         // 5.5M

    float* out      = (float*)d_out;
    float* user_out = out + (size_t)n_entities * DD;

    // workspace (~93 MB): bkt + gcur + iu + ui
    unsigned long long* bkt = (unsigned long long*)d_ws;        // 1024*6656*8 = 54.5 MB
    int* gcur = (int*)(bkt + (size_t)NBKT * CAP_B);             // 1024
    float* iu = (float*)(gcur + NBKT);                          // 50k*64 f32
    float* ui = iu + (size_t)n_items * DD;                      // 100k*64 f32

    // expectation-balanced bucket layout
    SegCfg cfg;
    {
        int nb[4];
        nb[0] = (int)((long long)nA * NBKT / Etot);
        nb[1] = (int)((long long)nB * NBKT / Etot);
        nb[2] = (int)((long long)nM * NBKT / Etot);
        nb[3] = NBKT - nb[0] - nb[1] - nb[2];
        int rows[4] = {n_entities, n_user_nodes, n_items, n_users};
        int soff[4] = {0, offB, offC, offD};
        int qb = 0;
        for (int s = 0; s < 4; ++s) {
            cfg.qbase[s] = qb;
            cfg.rpb[s]   = (rows[s] + nb[s] - 1) / nb[s];
            cfg.inv[s]   = 1.0f / (float)cfg.rpb[s];
            cfg.soff[s]  = soff[s];
            cfg.rows[s]  = rows[s];
            qb += nb[s];
        }
    }

    hipMemsetAsync(gcur, 0, NBKT * sizeof(int), stream);

    int nchunk = (Etot + CHUNK - 1) / CHUNK;    // 672
    split_kernel<<<nchunk, 512, 0, stream>>>(edge_index, edge_index + nA, edge_type,
                                             uedge_index, uedge_index + nB, uedge_type,
                                             mat_col, mat_row,
                                             mat_row, mat_col,
                                             nA, nB, nM, nM, cfg, gcur, bkt);
    sort_gather<<<NBKT, 512, 0, stream>>>(bkt, gcur, cfg,
                                          entity_emb, user_emb, weight,
                                          out, user_out, iu, ui);

    // items: gi = sig(kg@g1.T + iu@g2.T); out = gi*kg + (1-gi)*iu   (in-place kg)
    gate_fuse_kernel<<<1024, 256, 0, stream>>>(out, iu, g1, g2, out, n_items);
    // users: hi = sig(ukg@g3.T + ui@g2.T); out = hi*ukg + (1-hi)*ui (in-place ukg)
    gate_fuse_kernel<<<1024, 256, 0, stream>>>(user_out, ui, g3, g2, user_out, n_users);
}

// Round 11
// 527.840 us; speedup vs baseline: 1.1721x; 1.1721x over previous
//
#include <hip/hip_runtime.h>

#define DD 64
#define NBKT 1024
#define CHUNK 8192
#define CAP_B 6656    // bucket capacity in edges (mean 5371, ~17 sigma slack)

struct SegCfg {
    int qbase[4];   // first bucket id of segment
    int rpb[4];     // rows per bucket
    float inv[4];   // 1.f / rpb
    int soff[4];    // global row offset of segment
    int rows[4];    // rows in segment
};

// ---------- K1 (v2): 1024-way multisplit, staged + dense streamout ----------
// R9's two-pass direct scatter regressed (+54us): consecutive lanes hit 64
// different buckets -> 64 scattered 8B stores per wave. This staged version
// (measured ~175us in R7/R8) reorders in LDS so streamout writes contiguous runs.
__global__ void __launch_bounds__(512, 2)
split_kernel(const int* __restrict__ dA, const int* __restrict__ sA, const int* __restrict__ tA,
             const int* __restrict__ dB, const int* __restrict__ sB, const int* __restrict__ tB,
             const int* __restrict__ dC, const int* __restrict__ sC,
             const int* __restrict__ dD, const int* __restrict__ sD,
             int nA, int nB, int nC, int nD,
             SegCfg cfg, int* __restrict__ gcur, unsigned long long* __restrict__ bkt) {
    __shared__ unsigned long long ord[CHUNK];   // 64 KB
    __shared__ int cnt[NBKT];                   // 4 KB
    __shared__ int sc[NBKT];                    // 4 KB
    __shared__ int gb[NBKT];                    // 4 KB (scan scratch, then bases)
    int t = threadIdx.x;
    int Etot = nA + nB + nC + nD;
    int base = blockIdx.x * CHUNK;
    if (base >= Etot) return;

    cnt[t] = 0; cnt[t + 512] = 0;
    __syncthreads();

    unsigned long long val[16];
    int qv[16], rv[16];
#pragma unroll
    for (int k = 0; k < 16; ++k) {
        int i = base + k * 512 + t;
        qv[k] = -1;
        if (i < Etot) {
            int j = i, d, seg, pv;
            if (j < nA)              { seg = 0; d = dA[j]; pv = sA[j] | (tA[j] << 20); }
            else if ((j -= nA) < nB) { seg = 1; d = dB[j]; pv = sB[j] | (tB[j] << 20); }
            else if ((j -= nB) < nC) { seg = 2; d = dC[j]; pv = sC[j]; }
            else { j -= nC;            seg = 3; d = dD[j]; pv = sD[j]; }
            int rpb = cfg.rpb[seg];
            int q = (int)((float)d * cfg.inv[seg]);
            if (d >= (q + 1) * rpb) ++q;
            else if (d < q * rpb) --q;
            int g = d + cfg.soff[seg];
            q += cfg.qbase[seg];
            val[k] = ((unsigned long long)q << 44) | ((unsigned long long)g << 25) | (unsigned)pv;
            qv[k] = q;
            rv[k] = atomicAdd(&cnt[q], 1);
        }
    }
    __syncthreads();

    // exclusive scan of cnt[0..1024): 2 elems/thread, gb[] as partial scratch
    int c0 = cnt[2 * t], c1 = cnt[2 * t + 1];
    {
        int s2 = c0 + c1;
        gb[t] = s2;
        __syncthreads();
        for (int off = 1; off < 512; off <<= 1) {
            int x = (t >= off) ? gb[t - off] : 0;
            __syncthreads();
            gb[t] += x;
            __syncthreads();
        }
        int run = gb[t] - s2;
        sc[2 * t] = run;
        sc[2 * t + 1] = run + c0;
    }
    __syncthreads();
    // per-bucket global bases (overwrite gb)
    gb[2 * t]     = c0 ? atomicAdd(&gcur[2 * t], c0) : 0;
    gb[2 * t + 1] = c1 ? atomicAdd(&gcur[2 * t + 1], c1) : 0;
    __syncthreads();

#pragma unroll
    for (int k = 0; k < 16; ++k)
        if (qv[k] >= 0) ord[sc[qv[k]] + rv[k]] = val[k];
    __syncthreads();

    // full-lane dense streamout (capacity-clamped: overflow drops, never faults)
    int tot = sc[NBKT - 1] + cnt[NBKT - 1];
    for (int i = t; i < tot; i += 512) {
        unsigned long long v = ord[i];
        int q = (int)(v >> 44);
        int idx = gb[q] + (i - sc[q]);
        if (idx < CAP_B)
            bkt[(size_t)q * CAP_B + idx] = v & 0xFFFFFFFFFFFULL;
    }
}

// ---------- K2: fused per-bucket counting sort + gather-reduce (unchanged) ----------
__global__ void __launch_bounds__(512, 2)
sort_gather(const unsigned long long* __restrict__ bkt, const int* __restrict__ gcur,
            SegCfg cfg,
            const float* __restrict__ entity_emb, const float* __restrict__ user_emb,
            const float* __restrict__ weight,
            float* __restrict__ out, float* __restrict__ usr_out,
            float* __restrict__ iu, float* __restrict__ ui) {
    __shared__ int cnt[1024];        // 4 KB (rows/bucket <= 807)
    __shared__ int part[512];        // 2 KB
    __shared__ int stage[CAP_B];     // 26 KB
    int b = blockIdx.x, t = threadIdx.x;

    int seg = 0;
    if (b >= cfg.qbase[3]) seg = 3;
    else if (b >= cfg.qbase[2]) seg = 2;
    else if (b >= cfg.qbase[1]) seg = 1;
    int lb = b - cfg.qbase[seg];
    int row0 = cfg.soff[seg] + lb * cfg.rpb[seg];
    int nr = cfg.rows[seg] - lb * cfg.rpb[seg];
    if (nr > cfg.rpb[seg]) nr = cfg.rpb[seg];
    int n = gcur[b];
    if (n > CAP_B) n = CAP_B;        // overflow guard (matches split clamp)
    const unsigned long long* src = bkt + (size_t)b * CAP_B;

    // block-uniform source table and destination base
    const float* emb = (seg == 0 || seg == 3) ? entity_emb : user_emb;
    float* dbase;
    if (seg == 0)      dbase = out     + (size_t)row0 * DD;
    else if (seg == 1) dbase = usr_out + (size_t)(row0 - cfg.soff[1]) * DD;
    else if (seg == 2) dbase = iu      + (size_t)(row0 - cfg.soff[2]) * DD;
    else               dbase = ui      + (size_t)(row0 - cfg.soff[3]) * DD;

    cnt[t] = 0; cnt[t + 512] = 0;
    __syncthreads();
    for (int i = t; i < n; i += 512) {
        int g = (int)(src[i] >> 25);
        atomicAdd(&cnt[g - row0], 1);
    }
    __syncthreads();

    // exclusive scan of cnt[0..1024): 2 elems/thread + scan of partials
    {
        int c0 = cnt[2 * t], c1 = cnt[2 * t + 1];
        int s2 = c0 + c1;
        part[t] = s2;
        __syncthreads();
        for (int off = 1; off < 512; off <<= 1) {
            int y = (t >= off) ? part[t - off] : 0;
            __syncthreads();
            part[t] += y;
            __syncthreads();
        }
        int run = part[t] - s2;
        cnt[2 * t] = run;
        cnt[2 * t + 1] = run + c0;
    }
    __syncthreads();

    // scatter payloads into LDS stage (cnt consumed as cursors -> cnt[r] = row end)
    for (int i = t; i < n; i += 512) {
        unsigned long long v = src[i];
        int lr = (int)(v >> 25) - row0;
        int pos = atomicAdd(&cnt[lr], 1);
        stage[pos] = (int)(v & 0x1FFFFFF);
    }
    __syncthreads();

    // per-row gather-reduce: wave per row, payload broadcast from LDS
    int wv = t >> 6, lane = t & 63;
    for (int r = wv; r < nr; r += 8) {
        int start = (r == 0) ? 0 : cnt[r - 1];
        int end = cnt[r];
        float acc = 0.f;
        for (int base = start; base < end; base += 64) {
            int m = end - base; if (m > 64) m = 64;
            int pv = (lane < m) ? stage[base + lane] : 0;
            int j = 0;
            for (; j + 4 <= m; j += 4) {
                int p0 = __builtin_amdgcn_readlane(pv, j);
                int p1 = __builtin_amdgcn_readlane(pv, j + 1);
                int p2 = __builtin_amdgcn_readlane(pv, j + 2);
                int p3 = __builtin_amdgcn_readlane(pv, j + 3);
                const float* r0 = emb + (((unsigned)p0 & 0xFFFFFu) << 6);
                const float* r1 = emb + (((unsigned)p1 & 0xFFFFFu) << 6);
                const float* r2 = emb + (((unsigned)p2 & 0xFFFFFu) << 6);
                const float* r3 = emb + (((unsigned)p3 & 0xFFFFFu) << 6);
                float e0 = r0[lane], w0 = weight[(((unsigned)p0 >> 20) << 6) + lane];
                float e1 = r1[lane], w1 = weight[(((unsigned)p1 >> 20) << 6) + lane];
                float e2 = r2[lane], w2 = weight[(((unsigned)p2 >> 20) << 6) + lane];
                float e3 = r3[lane], w3 = weight[(((unsigned)p3 >> 20) << 6) + lane];
                acc += e0 * w0; acc += e1 * w1; acc += e2 * w2; acc += e3 * w3;
            }
            for (; j < m; ++j) {
                int pj = __builtin_amdgcn_readlane(pv, j);
                const float* rj = emb + (((unsigned)pj & 0xFFFFFu) << 6);
                acc += rj[lane] * weight[(((unsigned)pj >> 20) << 6) + lane];
            }
        }
        int deg = end - start;
        dbase[(size_t)r * DD + lane] = acc / (float)(deg > 0 ? deg : 1);
    }
}

// ---------- gated fusion v3: W in VGPRs, activation broadcast via v_readlane ----------
// v1 used __shfl (ds_bpermute: LDS-pipe-bound). v2 used readfirstlane + uniform
// loads (s_load: 77MB streamed through the scalar K$, ~150us by ledger). v3:
// each lane loads its own element coalesced (1 VMEM/row/matrix) and the fully
// unrolled dot broadcasts a[k] with v_readlane (VALU pipe, no LDS, no K$).
__global__ void __launch_bounds__(256)
gate_fuse_kernel(const float* __restrict__ a_, const float* __restrict__ b_,
                 const float* __restrict__ gA, const float* __restrict__ gB,
                 float* __restrict__ out, int n_rows) {
    int lane = threadIdx.x & 63;
    float wa[DD], wb[DD];
    {
        const float4* ga4 = (const float4*)(gA + (lane << 6));
        const float4* gb4 = (const float4*)(gB + (lane << 6));
#pragma unroll
        for (int k4 = 0; k4 < 16; ++k4) {
            float4 va = ga4[k4];
            float4 vb = gb4[k4];
            wa[4 * k4 + 0] = va.x; wa[4 * k4 + 1] = va.y;
            wa[4 * k4 + 2] = va.z; wa[4 * k4 + 3] = va.w;
            wb[4 * k4 + 0] = vb.x; wb[4 * k4 + 1] = vb.y;
            wb[4 * k4 + 2] = vb.z; wb[4 * k4 + 3] = vb.w;
        }
    }
    int wid = blockIdx.x * (blockDim.x >> 6) + (threadIdx.x >> 6);
    int nw = gridDim.x * (blockDim.x >> 6);
    for (int row = wid; row < n_rows; row += nw) {
        float av = a_[((size_t)row << 6) + lane];
        float bv = b_[((size_t)row << 6) + lane];
        int avi = __float_as_int(av), bvi = __float_as_int(bv);
        float z = 0.f;
#pragma unroll
        for (int k = 0; k < DD; ++k)
            z = fmaf(__int_as_float(__builtin_amdgcn_readlane(avi, k)), wa[k], z);
#pragma unroll
        for (int k = 0; k < DD; ++k)
            z = fmaf(__int_as_float(__builtin_amdgcn_readlane(bvi, k)), wb[k], z);
        float g = 1.f / (1.f + expf(-z));
        out[((size_t)row << 6) + lane] = g * av + (1.f - g) * bv;
    }
}

extern "C" void kernel_launch(void* const* d_in, const int* in_sizes, int n_in,
                              void* d_out, int out_size, void* d_ws, size_t ws_size,
                              hipStream_t stream) {
    const float* entity_emb = (const float*)d_in[0];
    const float* user_emb   = (const float*)d_in[1];
    const float* weight     = (const float*)d_in[2];
    const float* g1         = (const float*)d_in[3];
    const float* g2         = (const float*)d_in[4];
    const float* g3         = (const float*)d_in[5];
    const int* edge_index  = (const int*)d_in[6];
    const int* edge_type   = (const int*)d_in[7];
    const int* uedge_index = (const int*)d_in[8];
    const int* uedge_type  = (const int*)d_in[9];
    const int* mat_row     = (const int*)d_in[10];
    const int* mat_col     = (const int*)d_in[11];

    const int n_entities   = in_sizes[0] / DD;  // 180000
    const int n_user_nodes = in_sizes[1] / DD;  // 150000
    const int nA           = in_sizes[7];       // 1500000
    const int nB           = in_sizes[9];       // 1000000
    const int nM           = in_sizes[10];      // 1500000
    const int n_items      = 50000;
    const int n_users      = 100000;

    const int offB = n_entities;                // 180000
    const int offC = offB + n_user_nodes;       // 330000
    const int offD = offC + n_items;            // 380000
    const int Etot = nA + nB + nM + nM;         // 5.5M

    float* out      = (float*)d_out;
    float* user_out = out + (size_t)n_entities * DD;

    // workspace (~93 MB): bkt + gcur + iu + ui
    unsigned long long* bkt = (unsigned long long*)d_ws;        // 1024*6656*8 = 54.5 MB
    int* gcur = (int*)(bkt + (size_t)NBKT * CAP_B);             // 1024
    float* iu = (float*)(gcur + NBKT);                          // 50k*64 f32
    float* ui = iu + (size_t)n_items * DD;                      // 100k*64 f32

    // expectation-balanced bucket layout
    SegCfg cfg;
    {
        int nb[4];
        nb[0] = (int)((long long)nA * NBKT / Etot);
        nb[1] = (int)((long long)nB * NBKT / Etot);
        nb[2] = (int)((long long)nM * NBKT / Etot);
        nb[3] = NBKT - nb[0] - nb[1] - nb[2];
        int rows[4] = {n_entities, n_user_nodes, n_items, n_users};
        int soff[4] = {0, offB, offC, offD};
        int qb = 0;
        for (int s = 0; s < 4; ++s) {
            cfg.qbase[s] = qb;
            cfg.rpb[s]   = (rows[s] + nb[s] - 1) / nb[s];
            cfg.inv[s]   = 1.0f / (float)cfg.rpb[s];
            cfg.soff[s]  = soff[s];
            cfg.rows[s]  = rows[s];
            qb += nb[s];
        }
    }

    hipMemsetAsync(gcur, 0, NBKT * sizeof(int), stream);

    int nchunk = (Etot + CHUNK - 1) / CHUNK;    // 672
    split_kernel<<<nchunk, 512, 0, stream>>>(edge_index, edge_index + nA, edge_type,
                                             uedge_index, uedge_index + nB, uedge_type,
                                             mat_col, mat_row,
                                             mat_row, mat_col,
                                             nA, nB, nM, nM, cfg, gcur, bkt);
    sort_gather<<<NBKT, 512, 0, stream>>>(bkt, gcur, cfg,
                                          entity_emb, user_emb, weight,
                                          out, user_out, iu, ui);

    // items: gi = sig(kg@g1.T + iu@g2.T); out = gi*kg + (1-gi)*iu   (in-place kg)
    gate_fuse_kernel<<<1024, 256, 0, stream>>>(out, iu, g1, g2, out, n_items);
    // users: hi = sig(ukg@g3.T + ui@g2.T); out = hi*ukg + (1-hi)*ui (in-place ukg)
    gate_fuse_kernel<<<1024, 256, 0, stream>>>(user_out, ui, g3, g2, user_out, n_users);
}

// Round 12
// 527.069 us; speedup vs baseline: 1.1739x; 1.0015x over previous
//
#include <hip/hip_runtime.h>

#define DD 64
#define NBKT 1024
#define CHUNK 8192
#define CAP_B 6656    // bucket capacity in edges (mean 5371, ~17 sigma slack)

struct SegCfg {
    int qbase[4];   // first bucket id of segment
    int rpb[4];     // rows per bucket
    int soff[4];    // global row offset of segment
    int rows[4];    // rows in segment
};

struct SplitCfg {
    int cbase[4];        // first chunk (block) id of segment
    int nseg[4];         // edges in segment
    unsigned magic[4];   // ceil(2^32 / rpb): q = mulhi(d, magic) == d / rpb exactly
    int qbase[4];
    int soff[4];
};

// ---------- K1 v4: segment-uniform multisplit, magic-div, delta streamout ----------
// Same staged algorithm as v2 (classify -> LDS scan -> reorder -> dense streamout,
// measured correct R7/R8/R11), with the per-edge machinery stripped:
//  - grid partitioned by segment on host: seg/pointers/magic/qbase/soff are
//    block-scalar SGPRs, no per-edge 4-way branch;
//  - bucket = mul_hi_u32(d, ceil(2^32/rpb)) - exact for d < 2^18 (err < 2^-14);
//  - streamout address = i + delta[q] with delta = gb - sc folded once per bucket.
__global__ void __launch_bounds__(512, 2)
split_kernel(const int* __restrict__ dA, const int* __restrict__ sA, const int* __restrict__ tA,
             const int* __restrict__ dB, const int* __restrict__ sB, const int* __restrict__ tB,
             const int* __restrict__ dC, const int* __restrict__ sC,
             const int* __restrict__ dD, const int* __restrict__ sD,
             SplitCfg c, int* __restrict__ gcur, unsigned long long* __restrict__ bkt) {
    __shared__ unsigned long long ord[CHUNK];   // 64 KB
    __shared__ int cnt[NBKT];                   // 4 KB
    __shared__ int sc[NBKT];                    // 4 KB
    __shared__ int gb[NBKT];                    // 4 KB (scan scratch -> delta)
    int t = threadIdx.x;
    int blk = blockIdx.x;

    // block-uniform segment resolve (SGPR)
    int seg = 0;
    if (blk >= c.cbase[3]) seg = 3;
    else if (blk >= c.cbase[2]) seg = 2;
    else if (blk >= c.cbase[1]) seg = 1;
    const int* dp; const int* sp; const int* tp;
    if (seg == 0)      { dp = dA; sp = sA; tp = tA; }
    else if (seg == 1) { dp = dB; sp = sB; tp = tB; }
    else if (seg == 2) { dp = dC; sp = sC; tp = nullptr; }
    else               { dp = dD; sp = sD; tp = nullptr; }
    unsigned Ms = c.magic[seg];
    int qb = c.qbase[seg];
    int e0 = (blk - c.cbase[seg]) * CHUNK;
    int n = c.nseg[seg] - e0;
    if (n > CHUNK) n = CHUNK;

    cnt[t] = 0; cnt[t + 512] = 0;
    __syncthreads();

    unsigned long long val[16];
    int qv[16], rv[16];
#pragma unroll
    for (int k = 0; k < 16; ++k) {
        int ii = k * 512 + t;
        qv[k] = -1;
        if (ii < n) {
            int d = dp[e0 + ii];
            int pv = sp[e0 + ii];
            if (tp) pv |= tp[e0 + ii] << 20;
            int q = __umulhi((unsigned)d, Ms) + qb;      // exact d / rpb + qbase
            int g = d + c.soff[seg];
            val[k] = ((unsigned long long)q << 44) | ((unsigned long long)g << 25) | (unsigned)pv;
            qv[k] = q;
            rv[k] = atomicAdd(&cnt[q], 1);
        }
    }
    __syncthreads();

    // exclusive scan of cnt[0..1024): 2 elems/thread, gb[] as partial scratch
    int c0 = cnt[2 * t], c1 = cnt[2 * t + 1];
    {
        int s2 = c0 + c1;
        gb[t] = s2;
        __syncthreads();
        for (int off = 1; off < 512; off <<= 1) {
            int x = (t >= off) ? gb[t - off] : 0;
            __syncthreads();
            gb[t] += x;
            __syncthreads();
        }
        int run = gb[t] - s2;
        sc[2 * t] = run;
        sc[2 * t + 1] = run + c0;
    }
    __syncthreads();
    // per-bucket global bases, folded immediately into delta = base - sc
    gb[2 * t]     = (c0 ? atomicAdd(&gcur[2 * t], c0) : 0) - sc[2 * t];
    gb[2 * t + 1] = (c1 ? atomicAdd(&gcur[2 * t + 1], c1) : 0) - sc[2 * t + 1];
    __syncthreads();

#pragma unroll
    for (int k = 0; k < 16; ++k)
        if (qv[k] >= 0) ord[sc[qv[k]] + rv[k]] = val[k];
    __syncthreads();

    // full-lane dense streamout (capacity-clamped: overflow drops, never faults)
    int tot = sc[NBKT - 1] + cnt[NBKT - 1];
    for (int i = t; i < tot; i += 512) {
        unsigned long long v = ord[i];
        int q = (int)(v >> 44);
        int idx = i + gb[q];                 // gb holds delta
        if ((unsigned)idx < CAP_B)
            bkt[(size_t)q * CAP_B + idx] = v & 0xFFFFFFFFFFFULL;
    }
}

// ---------- K2: fused per-bucket counting sort + gather-reduce (unchanged) ----------
__global__ void __launch_bounds__(512, 2)
sort_gather(const unsigned long long* __restrict__ bkt, const int* __restrict__ gcur,
            SegCfg cfg,
            const float* __restrict__ entity_emb, const float* __restrict__ user_emb,
            const float* __restrict__ weight,
            float* __restrict__ out, float* __restrict__ usr_out,
            float* __restrict__ iu, float* __restrict__ ui) {
    __shared__ int cnt[1024];        // 4 KB (rows/bucket <= 807)
    __shared__ int part[512];        // 2 KB
    __shared__ int stage[CAP_B];     // 26 KB
    int b = blockIdx.x, t = threadIdx.x;

    int seg = 0;
    if (b >= cfg.qbase[3]) seg = 3;
    else if (b >= cfg.qbase[2]) seg = 2;
    else if (b >= cfg.qbase[1]) seg = 1;
    int lb = b - cfg.qbase[seg];
    int row0 = cfg.soff[seg] + lb * cfg.rpb[seg];
    int nr = cfg.rows[seg] - lb * cfg.rpb[seg];
    if (nr > cfg.rpb[seg]) nr = cfg.rpb[seg];
    int n = gcur[b];
    if (n > CAP_B) n = CAP_B;        // overflow guard (matches split clamp)
    const unsigned long long* src = bkt + (size_t)b * CAP_B;

    // block-uniform source table and destination base
    const float* emb = (seg == 0 || seg == 3) ? entity_emb : user_emb;
    float* dbase;
    if (seg == 0)      dbase = out     + (size_t)row0 * DD;
    else if (seg == 1) dbase = usr_out + (size_t)(row0 - cfg.soff[1]) * DD;
    else if (seg == 2) dbase = iu      + (size_t)(row0 - cfg.soff[2]) * DD;
    else               dbase = ui      + (size_t)(row0 - cfg.soff[3]) * DD;

    cnt[t] = 0; cnt[t + 512] = 0;
    __syncthreads();
    for (int i = t; i < n; i += 512) {
        int g = (int)(src[i] >> 25);
        atomicAdd(&cnt[g - row0], 1);
    }
    __syncthreads();

    // exclusive scan of cnt[0..1024): 2 elems/thread + scan of partials
    {
        int c0 = cnt[2 * t], c1 = cnt[2 * t + 1];
        int s2 = c0 + c1;
        part[t] = s2;
        __syncthreads();
        for (int off = 1; off < 512; off <<= 1) {
            int y = (t >= off) ? part[t - off] : 0;
            __syncthreads();
            part[t] += y;
            __syncthreads();
        }
        int run = part[t] - s2;
        cnt[2 * t] = run;
        cnt[2 * t + 1] = run + c0;
    }
    __syncthreads();

    // scatter payloads into LDS stage (cnt consumed as cursors -> cnt[r] = row end)
    for (int i = t; i < n; i += 512) {
        unsigned long long v = src[i];
        int lr = (int)(v >> 25) - row0;
        int pos = atomicAdd(&cnt[lr], 1);
        stage[pos] = (int)(v & 0x1FFFFFF);
    }
    __syncthreads();

    // per-row gather-reduce: wave per row, payload broadcast from LDS
    int wv = t >> 6, lane = t & 63;
    for (int r = wv; r < nr; r += 8) {
        int start = (r == 0) ? 0 : cnt[r - 1];
        int end = cnt[r];
        float acc = 0.f;
        for (int base = start; base < end; base += 64) {
            int m = end - base; if (m > 64) m = 64;
            int pv = (lane < m) ? stage[base + lane] : 0;
            int j = 0;
            for (; j + 4 <= m; j += 4) {
                int p0 = __builtin_amdgcn_readlane(pv, j);
                int p1 = __builtin_amdgcn_readlane(pv, j + 1);
                int p2 = __builtin_amdgcn_readlane(pv, j + 2);
                int p3 = __builtin_amdgcn_readlane(pv, j + 3);
                const float* r0 = emb + (((unsigned)p0 & 0xFFFFFu) << 6);
                const float* r1 = emb + (((unsigned)p1 & 0xFFFFFu) << 6);
                const float* r2 = emb + (((unsigned)p2 & 0xFFFFFu) << 6);
                const float* r3 = emb + (((unsigned)p3 & 0xFFFFFu) << 6);
                float e0 = r0[lane], w0 = weight[(((unsigned)p0 >> 20) << 6) + lane];
                float e1 = r1[lane], w1 = weight[(((unsigned)p1 >> 20) << 6) + lane];
                float e2 = r2[lane], w2 = weight[(((unsigned)p2 >> 20) << 6) + lane];
                float e3 = r3[lane], w3 = weight[(((unsigned)p3 >> 20) << 6) + lane];
                acc += e0 * w0; acc += e1 * w1; acc += e2 * w2; acc += e3 * w3;
            }
            for (; j < m; ++j) {
                int pj = __builtin_amdgcn_readlane(pv, j);
                const float* rj = emb + (((unsigned)pj & 0xFFFFFu) << 6);
                acc += rj[lane] * weight[(((unsigned)pj >> 20) << 6) + lane];
            }
        }
        int deg = end - start;
        dbase[(size_t)r * DD + lane] = acc / (float)(deg > 0 ? deg : 1);
    }
}

// ---------- gated fusion v3 (unchanged): W in VGPRs, v_readlane broadcast ----------
__global__ void __launch_bounds__(256)
gate_fuse_kernel(const float* __restrict__ a_, const float* __restrict__ b_,
                 const float* __restrict__ gA, const float* __restrict__ gB,
                 float* __restrict__ out, int n_rows) {
    int lane = threadIdx.x & 63;
    float wa[DD], wb[DD];
    {
        const float4* ga4 = (const float4*)(gA + (lane << 6));
        const float4* gb4 = (const float4*)(gB + (lane << 6));
#pragma unroll
        for (int k4 = 0; k4 < 16; ++k4) {
            float4 va = ga4[k4];
            float4 vb = gb4[k4];
            wa[4 * k4 + 0] = va.x; wa[4 * k4 + 1] = va.y;
            wa[4 * k4 + 2] = va.z; wa[4 * k4 + 3] = va.w;
            wb[4 * k4 + 0] = vb.x; wb[4 * k4 + 1] = vb.y;
            wb[4 * k4 + 2] = vb.z; wb[4 * k4 + 3] = vb.w;
        }
    }
    int wid = blockIdx.x * (blockDim.x >> 6) + (threadIdx.x >> 6);
    int nw = gridDim.x * (blockDim.x >> 6);
    for (int row = wid; row < n_rows; row += nw) {
        float av = a_[((size_t)row << 6) + lane];
        float bv = b_[((size_t)row << 6) + lane];
        int avi = __float_as_int(av), bvi = __float_as_int(bv);
        float z = 0.f;
#pragma unroll
        for (int k = 0; k < DD; ++k)
            z = fmaf(__int_as_float(__builtin_amdgcn_readlane(avi, k)), wa[k], z);
#pragma unroll
        for (int k = 0; k < DD; ++k)
            z = fmaf(__int_as_float(__builtin_amdgcn_readlane(bvi, k)), wb[k], z);
        float g = 1.f / (1.f + expf(-z));
        out[((size_t)row << 6) + lane] = g * av + (1.f - g) * bv;
    }
}

extern "C" void kernel_launch(void* const* d_in, const int* in_sizes, int n_in,
                              void* d_out, int out_size, void* d_ws, size_t ws_size,
                              hipStream_t stream) {
    const float* entity_emb = (const float*)d_in[0];
    const float* user_emb   = (const float*)d_in[1];
    const float* weight     = (const float*)d_in[2];
    const float* g1         = (const float*)d_in[3];
    const float* g2         = (const float*)d_in[4];
    const float* g3         = (const float*)d_in[5];
    const int* edge_index  = (const int*)d_in[6];
    const int* edge_type   = (const int*)d_in[7];
    const int* uedge_index = (const int*)d_in[8];
    const int* uedge_type  = (const int*)d_in[9];
    const int* mat_row     = (const int*)d_in[10];
    const int* mat_col     = (const int*)d_in[11];

    const int n_entities   = in_sizes[0] / DD;  // 180000
    const int n_user_nodes = in_sizes[1] / DD;  // 150000
    const int nA           = in_sizes[7];       // 1500000
    const int nB           = in_sizes[9];       // 1000000
    const int nM           = in_sizes[10];      // 1500000
    const int n_items      = 50000;
    const int n_users      = 100000;

    const int offB = n_entities;                // 180000
    const int offC = offB + n_user_nodes;       // 330000
    const int offD = offC + n_items;            // 380000
    const int Etot = nA + nB + nM + nM;         // 5.5M

    float* out      = (float*)d_out;
    float* user_out = out + (size_t)n_entities * DD;

    // workspace (~93 MB): bkt + gcur + iu + ui
    unsigned long long* bkt = (unsigned long long*)d_ws;        // 1024*6656*8 = 54.5 MB
    int* gcur = (int*)(bkt + (size_t)NBKT * CAP_B);             // 1024
    float* iu = (float*)(gcur + NBKT);                          // 50k*64 f32
    float* ui = iu + (size_t)n_items * DD;                      // 100k*64 f32

    // expectation-balanced bucket layout (shared by both kernels)
    SegCfg cfg;
    SplitCfg sc2;
    {
        int nb[4];
        nb[0] = (int)((long long)nA * NBKT / Etot);
        nb[1] = (int)((long long)nB * NBKT / Etot);
        nb[2] = (int)((long long)nM * NBKT / Etot);
        nb[3] = NBKT - nb[0] - nb[1] - nb[2];
        int rows[4] = {n_entities, n_user_nodes, n_items, n_users};
        int soff[4] = {0, offB, offC, offD};
        int nseg[4] = {nA, nB, nM, nM};
        int qb = 0, cb = 0;
        for (int s = 0; s < 4; ++s) {
            int rpb = (rows[s] + nb[s] - 1) / nb[s];
            cfg.qbase[s] = qb;
            cfg.rpb[s]   = rpb;
            cfg.soff[s]  = soff[s];
            cfg.rows[s]  = rows[s];
            sc2.cbase[s] = cb;
            sc2.nseg[s]  = nseg[s];
            sc2.magic[s] = (unsigned)((0x100000000ULL + rpb - 1) / rpb);  // ceil(2^32/rpb)
            sc2.qbase[s] = qb;
            sc2.soff[s]  = soff[s];
            qb += nb[s];
            cb += (nseg[s] + CHUNK - 1) / CHUNK;
        }
        hipMemsetAsync(gcur, 0, NBKT * sizeof(int), stream);

        split_kernel<<<cb, 512, 0, stream>>>(edge_index, edge_index + nA, edge_type,
                                             uedge_index, uedge_index + nB, uedge_type,
                                             mat_col, mat_row,
                                             mat_row, mat_col,
                                             sc2, gcur, bkt);
    }

    sort_gather<<<NBKT, 512, 0, stream>>>(bkt, gcur, cfg,
                                          entity_emb, user_emb, weight,
                                          out, user_out, iu, ui);

    // items: gi = sig(kg@g1.T + iu@g2.T); out = gi*kg + (1-gi)*iu   (in-place kg)
    gate_fuse_kernel<<<1024, 256, 0, stream>>>(out, iu, g1, g2, out, n_items);
    // users: hi = sig(ukg@g3.T + ui@g2.T); out = hi*ukg + (1-hi)*ui (in-place ukg)
    gate_fuse_kernel<<<1024, 256, 0, stream>>>(user_out, ui, g3, g2, user_out, n_users);
}